// Round 19
// baseline (748.224 us; speedup 1.0000x reference)
//
#include <hip/hip_runtime.h>
#include <cstdint>
#include <cstddef>

#define DIM     1024
#define SEQ     2048
#define BATCH   2
#define DEPTH   2
#define D_INNER 2048
#define D_STATE 16
#define D_CONV  4
#define DT_RANK 64
#define FF      4096
#define ROWS    (BATCH*SEQ)   // 4096
#define EPS     1e-5f

#define CS      32            // scan chunk size
#define NC      (SEQ/CS)      // 64 chunks
#define NC_LOG  6

#define XP_KS    8            // x_proj k-split
#define XP_KSTEP (D_INNER/XP_KS)  // 256

#define LOG2E 1.44269504088896f

typedef unsigned short ushort_t;
typedef short bf16x8 __attribute__((ext_vector_type(8)));
typedef float f32x4  __attribute__((ext_vector_type(4)));

__device__ __forceinline__ float sigmoidf_(float x) { return 1.f / (1.f + __expf(-x)); }

// bf16 <-> fp32
__device__ __forceinline__ ushort_t f2bf(float x) {
  unsigned int u = __float_as_uint(x);
  u += 0x7fffu + ((u >> 16) & 1u);
  return (ushort_t)(u >> 16);
}
__device__ __forceinline__ float bf2f(ushort_t u) {
  return __uint_as_float((unsigned)u << 16);
}

// async global->LDS 16B (wave-uniform LDS base + lane*16)
__device__ __forceinline__ void async_cp16(const void* g, void* lds) {
  __builtin_amdgcn_global_load_lds(
      (const __attribute__((address_space(1))) unsigned int*)g,
      (__attribute__((address_space(3))) unsigned int*)lds, 16, 0, 0);
}

// ---------------- block-wide reduction ----------------
__device__ __forceinline__ float2 block_sum2(float a, float b) {
#pragma unroll
  for (int off = 32; off > 0; off >>= 1) {
    a += __shfl_down(a, off, 64);
    b += __shfl_down(b, off, 64);
  }
  __shared__ float sa[4], sb[4];
  __syncthreads();
  if ((threadIdx.x & 63) == 0) { int w = threadIdx.x >> 6; sa[w] = a; sb[w] = b; }
  __syncthreads();
  return make_float2(sa[0] + sa[1] + sa[2] + sa[3], sb[0] + sb[1] + sb[2] + sb[3]);
}

// ---------------- residual add + RMSNorm (bf16 normed out) ----------------
__global__ __launch_bounds__(256) void res_rms_kernel(
    const float* __restrict__ xin,
    float* __restrict__ res, ushort_t* __restrict__ nrm, const float* __restrict__ w) {
  int row = blockIdx.x;
  const float* xr = xin + (size_t)row * DIM;
  float* rr = res + (size_t)row * DIM;
  ushort_t* nr = nrm + (size_t)row * DIM;
  float v[4]; float ss = 0.f;
#pragma unroll
  for (int i = 0; i < 4; ++i) {
    int j = threadIdx.x + i * 256;
    float t = xr[j];
    v[i] = t; rr[j] = t; ss += t * t;
  }
  float2 s = block_sum2(ss, 0.f);
  float rstd = rsqrtf(s.x * (1.f / DIM) + EPS);
#pragma unroll
  for (int i = 0; i < 4; ++i) {
    int j = threadIdx.x + i * 256;
    nr[j] = f2bf(v[i] * rstd * w[j]);
  }
}

// ---------------- fused LayerNorm -> residual add -> RMSNorm (bf16 out) ----------------
__global__ __launch_bounds__(256) void ln_res_rms_kernel(
    const float* __restrict__ in, float* __restrict__ res,
    const float* __restrict__ lw, const float* __restrict__ lb,
    const float* __restrict__ rw, ushort_t* __restrict__ nrm) {
  int row = blockIdx.x;
  const float* xr = in + (size_t)row * DIM;
  float* rr = res + (size_t)row * DIM;
  ushort_t* nr = nrm + (size_t)row * DIM;
  float v[4]; float s1 = 0.f, s2 = 0.f;
#pragma unroll
  for (int i = 0; i < 4; ++i) {
    int j = threadIdx.x + i * 256;
    float t = xr[j];
    v[i] = t; s1 += t; s2 += t * t;
  }
  float2 s = block_sum2(s1, s2);
  float mean = s.x * (1.f / DIM);
  float var = s.y * (1.f / DIM) - mean * mean;
  float rstd = rsqrtf(var + EPS);
  float t4[4]; float ss = 0.f;
#pragma unroll
  for (int i = 0; i < 4; ++i) {
    int j = threadIdx.x + i * 256;
    float o = (v[i] - mean) * rstd * lw[j] + lb[j];
    float t = rr[j] + o;
    rr[j] = t;
    t4[i] = t; ss += t * t;
  }
  float2 s2v = block_sum2(ss, 0.f);
  float rstd2 = rsqrtf(s2v.x * (1.f / DIM) + EPS);
#pragma unroll
  for (int i = 0; i < 4; ++i) {
    int j = threadIdx.x + i * 256;
    nr[j] = f2bf(t4[i] * rstd2 * rw[j]);
  }
}

// ---------------- final LayerNorm (bf16 out only) ----------------
__global__ __launch_bounds__(256) void ln_final_kernel(
    const float* __restrict__ in, ushort_t* __restrict__ outb,
    const float* __restrict__ w, const float* __restrict__ b) {
  int row = blockIdx.x;
  const float* xr = in + (size_t)row * DIM;
  ushort_t* obrow = outb + (size_t)row * DIM;
  float v[4]; float s1 = 0.f, s2 = 0.f;
#pragma unroll
  for (int i = 0; i < 4; ++i) {
    int j = threadIdx.x + i * 256;
    float t = xr[j];
    v[i] = t; s1 += t; s2 += t * t;
  }
  float2 s = block_sum2(s1, s2);
  float mean = s.x * (1.f / DIM);
  float var = s.y * (1.f / DIM) - mean * mean;
  float rstd = rsqrtf(var + EPS);
#pragma unroll
  for (int i = 0; i < 4; ++i) {
    int j = threadIdx.x + i * 256;
    obrow[j] = f2bf((v[i] - mean) * rstd * w[j] + b[j]);
  }
}

// ---------------- fused fp32 -> bf16 conversion for all 4 weight tensors ----------------
__global__ __launch_bounds__(256) void f2b_all(
    const float* __restrict__ w0, ushort_t* __restrict__ d0,
    const float* __restrict__ w1, ushort_t* __restrict__ d1,
    const float* __restrict__ w2, ushort_t* __restrict__ d2,
    const float* __restrict__ w3, ushort_t* __restrict__ d3) {
  int i = (blockIdx.x * 256 + threadIdx.x) * 4;
  const float* s; ushort_t* d; int off;
  if (i < 8388608)        { s = w0; d = d0; off = i; }
  else if (i < 12582912)  { s = w1; d = d1; off = i - 8388608; }
  else if (i < 20971520)  { s = w2; d = d2; off = i - 12582912; }
  else                    { s = w3; d = d3; off = i - 20971520; }
  float4 v = *reinterpret_cast<const float4*>(s + off);
  d[off + 0] = f2bf(v.x); d[off + 1] = f2bf(v.y);
  d[off + 2] = f2bf(v.z); d[off + 3] = f2bf(v.w);
}

// ---------------- bf16 MFMA NT GEMM: C = A[M,K] * B[N,K]^T (+bias) ----------------
// 128x128 tile, BK=64, 4 waves (2x2), 16x16x32 MFMA.
// DOUBLE-BUFFERED LDS + counted vmcnt (helps K-deep in_proj; kept per R15/16 A/B).
__global__ __launch_bounds__(256) void gemm_bf16_nt(
    const ushort_t* __restrict__ A,
    const ushort_t* __restrict__ B,
    float* __restrict__ C,
    ushort_t* __restrict__ Cb,
    int N, int K,
    const float* __restrict__ bias, int grp) {
  __shared__ ushort_t As[2][128 * 64];
  __shared__ ushort_t Bs[2][128 * 64];
  const int tid = threadIdx.x;
  const int l = tid & 63;
  const int w = tid >> 6;

  const unsigned nwgx = gridDim.x;
  const unsigned nwg = nwgx * gridDim.y;
  const unsigned bid = blockIdx.y * nwgx + blockIdx.x;
  const unsigned cpx = nwg >> 3;
  const unsigned s = (bid & 7u) * cpx + (bid >> 3);
  const unsigned bandw = (unsigned)grp * nwgx;
  const unsigned band = s / bandw;
  const unsigned rem = s % bandw;
  const int m0 = (int)(band * grp + (rem % grp)) * 128;
  const int n0 = (int)(rem / grp) * 128;

  const int wm = (w >> 1) * 64;
  const int wn = (w & 1) * 64;

  const int srow = l >> 3;                      // 0..7 (row within 8-row chunk)
  const int ksrc = 8 * ((l & 7) ^ srow);        // swizzled source k-offset (elements)
  const int kg = l >> 4;                        // 0..3
  const int lr = l & 15;

  f32x4 acc[4][4];
#pragma unroll
  for (int mi = 0; mi < 4; ++mi)
#pragma unroll
    for (int ni = 0; ni < 4; ++ni) acc[mi][ni] = (f32x4)0.f;

  const int nt = K >> 6;

#define STAGE_NT(buf, t)                                                      \
  do {                                                                        \
    int k0_ = (t) << 6;                                                       \
    _Pragma("unroll")                                                         \
    for (int j = 0; j < 4; ++j) {                                             \
      int c = j * 4 + w;                                                      \
      int r = c * 8 + srow;                                                   \
      async_cp16(&A[(size_t)(m0 + r) * K + k0_ + ksrc], &As[buf][c * 512]);   \
    }                                                                         \
    _Pragma("unroll")                                                         \
    for (int j = 0; j < 4; ++j) {                                             \
      int c = j * 4 + w;                                                      \
      int r = c * 8 + srow;                                                   \
      async_cp16(&B[(size_t)(n0 + r) * K + k0_ + ksrc], &Bs[buf][c * 512]);   \
    }                                                                         \
  } while (0)

#define COMPUTE_NT(buf)                                                       \
  do {                                                                        \
    _Pragma("unroll")                                                         \
    for (int ks = 0; ks < 2; ++ks) {                                          \
      bf16x8 af[4], bfr[4];                                                   \
      _Pragma("unroll")                                                       \
      for (int mi = 0; mi < 4; ++mi) {                                        \
        int r = wm + mi * 16 + lr;                                            \
        int boff = r * 128 + ((ks * 64 + kg * 16) ^ ((r & 7) << 4));          \
        af[mi] = *reinterpret_cast<const bf16x8*>(                            \
            reinterpret_cast<const char*>(As[buf]) + boff);                   \
      }                                                                       \
      _Pragma("unroll")                                                       \
      for (int ni = 0; ni < 4; ++ni) {                                        \
        int r = wn + ni * 16 + lr;                                            \
        int boff = r * 128 + ((ks * 64 + kg * 16) ^ ((r & 7) << 4));          \
        bfr[ni] = *reinterpret_cast<const bf16x8*>(                           \
            reinterpret_cast<const char*>(Bs[buf]) + boff);                   \
      }                                                                       \
      _Pragma("unroll")                                                       \
      for (int mi = 0; mi < 4; ++mi)                                          \
        _Pragma("unroll")                                                     \
        for (int ni = 0; ni < 4; ++ni)                                        \
          acc[mi][ni] = __builtin_amdgcn_mfma_f32_16x16x32_bf16(              \
              af[mi], bfr[ni], acc[mi][ni], 0, 0, 0);                         \
    }                                                                         \
  } while (0)

  STAGE_NT(0, 0);
  int cur = 0;
  for (int t = 0; t < nt; ++t) {
    if (t + 1 < nt) {
      STAGE_NT(cur ^ 1, t + 1);
      asm volatile("s_waitcnt vmcnt(8)" ::: "memory");
    } else {
      asm volatile("s_waitcnt vmcnt(0)" ::: "memory");
    }
    asm volatile("s_barrier" ::: "memory");
    COMPUTE_NT(cur);
    asm volatile("s_barrier" ::: "memory");
    cur ^= 1;
  }
#undef STAGE_NT
#undef COMPUTE_NT

  const int crow0 = (l >> 4) * 4;
  const int ccol = l & 15;
#pragma unroll
  for (int mi = 0; mi < 4; ++mi) {
#pragma unroll
    for (int ni = 0; ni < 4; ++ni) {
      int col = n0 + wn + ni * 16 + ccol;
      float bv = bias ? bias[col] : 0.f;
#pragma unroll
      for (int j = 0; j < 4; ++j) {
        int row = m0 + wm + mi * 16 + crow0 + j;
        float v = acc[mi][ni][j] + bv;
        if (Cb) Cb[(size_t)row * N + col] = f2bf(v);
        else    C[(size_t)row * N + col] = v;
      }
    }
  }
}

// ---------------- bf16 MFMA NT GEMM, 64x128 tile (for N=1024 GEMMs) ----------------
// DOUBLE-BUFFERED + counted vmcnt(6): deep-K, grid-limited to 2 blocks/CU.
__global__ __launch_bounds__(256) void gemm_bf16_nt64(
    const ushort_t* __restrict__ A,
    const ushort_t* __restrict__ B,
    float* __restrict__ C,
    int N, int K,
    const float* __restrict__ bias, int grp) {
  __shared__ ushort_t As[2][64 * 64];
  __shared__ ushort_t Bs[2][128 * 64];
  const int tid = threadIdx.x;
  const int l = tid & 63;
  const int w = tid >> 6;

  const unsigned nwgx = gridDim.x;
  const unsigned nwg = nwgx * gridDim.y;
  const unsigned bid = blockIdx.y * nwgx + blockIdx.x;
  const unsigned cpx = nwg >> 3;
  const unsigned s = (bid & 7u) * cpx + (bid >> 3);
  const unsigned bandw = (unsigned)grp * nwgx;
  const unsigned band = s / bandw;
  const unsigned rem = s % bandw;
  const int m0 = (int)(band * grp + (rem % grp)) * 64;
  const int n0 = (int)(rem / grp) * 128;

  const int wm = (w >> 1) * 32;
  const int wn = (w & 1) * 64;

  const int srow = l >> 3;
  const int ksrc = 8 * ((l & 7) ^ srow);
  const int kg = l >> 4;
  const int lr = l & 15;

  f32x4 acc[2][4];
#pragma unroll
  for (int mi = 0; mi < 2; ++mi)
#pragma unroll
    for (int ni = 0; ni < 4; ++ni) acc[mi][ni] = (f32x4)0.f;

  const int nt = K >> 6;

#define STAGE_64(buf, t)                                                      \
  do {                                                                        \
    int k0_ = (t) << 6;                                                       \
    _Pragma("unroll")                                                         \
    for (int j = 0; j < 2; ++j) {                                             \
      int c = j * 4 + w;                                                      \
      int r = c * 8 + srow;                                                   \
      async_cp16(&A[(size_t)(m0 + r) * K + k0_ + ksrc], &As[buf][c * 512]);   \
    }                                                                         \
    _Pragma("unroll")                                                         \
    for (int j = 0; j < 4; ++j) {                                             \
      int c = j * 4 + w;                                                      \
      int r = c * 8 + srow;                                                   \
      async_cp16(&B[(size_t)(n0 + r) * K + k0_ + ksrc], &Bs[buf][c * 512]);   \
    }                                                                         \
  } while (0)

#define COMPUTE_64(buf)                                                       \
  do {                                                                        \
    _Pragma("unroll")                                                         \
    for (int ks = 0; ks < 2; ++ks) {                                          \
      bf16x8 af[2], bfr[4];                                                   \
      _Pragma("unroll")                                                       \
      for (int mi = 0; mi < 2; ++mi) {                                        \
        int r = wm + mi * 16 + lr;                                            \
        int boff = r * 128 + ((ks * 64 + kg * 16) ^ ((r & 7) << 4));          \
        af[mi] = *reinterpret_cast<const bf16x8*>(                            \
            reinterpret_cast<const char*>(As[buf]) + boff);                   \
      }                                                                       \
      _Pragma("unroll")                                                       \
      for (int ni = 0; ni < 4; ++ni) {                                        \
        int r = wn + ni * 16 + lr;                                            \
        int boff = r * 128 + ((ks * 64 + kg * 16) ^ ((r & 7) << 4));          \
        bfr[ni] = *reinterpret_cast<const bf16x8*>(                           \
            reinterpret_cast<const char*>(Bs[buf]) + boff);                   \
      }                                                                       \
      _Pragma("unroll")                                                       \
      for (int mi = 0; mi < 2; ++mi)                                          \
        _Pragma("unroll")                                                     \
        for (int ni = 0; ni < 4; ++ni)                                        \
          acc[mi][ni] = __builtin_amdgcn_mfma_f32_16x16x32_bf16(              \
              af[mi], bfr[ni], acc[mi][ni], 0, 0, 0);                         \
    }                                                                         \
  } while (0)

  STAGE_64(0, 0);
  int cur = 0;
  for (int t = 0; t < nt; ++t) {
    if (t + 1 < nt) {
      STAGE_64(cur ^ 1, t + 1);
      asm volatile("s_waitcnt vmcnt(6)" ::: "memory");
    } else {
      asm volatile("s_waitcnt vmcnt(0)" ::: "memory");
    }
    asm volatile("s_barrier" ::: "memory");
    COMPUTE_64(cur);
    asm volatile("s_barrier" ::: "memory");
    cur ^= 1;
  }
#undef STAGE_64
#undef COMPUTE_64

  const int crow0 = (l >> 4) * 4;
  const int ccol = l & 15;
#pragma unroll
  for (int mi = 0; mi < 2; ++mi) {
#pragma unroll
    for (int ni = 0; ni < 4; ++ni) {
      int col = n0 + wn + ni * 16 + ccol;
      float bv = bias ? bias[col] : 0.f;
#pragma unroll
      for (int j = 0; j < 4; ++j) {
        int row = m0 + wm + mi * 16 + crow0 + j;
        C[(size_t)row * N + col] = acc[mi][ni][j] + bv;
      }
    }
  }
}

// ---------------- fused FFN1 + GEGLU, 128x32-out tile, dbuf+vmcnt(6) ----------------
// Tile: 128 M-rows x 32 out-cols (B rows: 32 a + 32 g). acc[4][2] = 32 VGPR.
// Grid (FF/32=128, M/128=32) = 4096 blocks; LDS 48KB -> 3 blocks/CU residency.
// Combines occupancy (R15 lesson) with the counted-vmcnt pipeline (R18 lesson).
__global__ __launch_bounds__(256) void gemm_ffn1_glu(
    const ushort_t* __restrict__ A,
    const ushort_t* __restrict__ B,
    ushort_t* __restrict__ O,
    int K,
    const float* __restrict__ bias, int grp) {
  __shared__ ushort_t As[2][128 * 64];
  __shared__ ushort_t Bs[2][64 * 64];
  const int tid = threadIdx.x;
  const int l = tid & 63;
  const int w = tid >> 6;

  const unsigned nwgx = gridDim.x;                // 128 col-panels of width 32
  const unsigned nwg = nwgx * gridDim.y;
  const unsigned bid = blockIdx.y * nwgx + blockIdx.x;
  const unsigned cpx = nwg >> 3;
  const unsigned s = (bid & 7u) * cpx + (bid >> 3);
  const unsigned bandw = (unsigned)grp * nwgx;
  const unsigned band = s / bandw;
  const unsigned rem = s % bandw;
  const int m0 = (int)(band * grp + (rem % grp)) * 128;
  const int n0 = (int)(rem / grp) * 32;

  const int wm = (w >> 1) * 64;
  const int wn2 = (w & 1) * 16;

  const int srow = l >> 3;
  const int ksrc = 8 * ((l & 7) ^ srow);
  const int kg = l >> 4;
  const int lr = l & 15;

  f32x4 acc[4][2];
#pragma unroll
  for (int mi = 0; mi < 4; ++mi)
#pragma unroll
    for (int ni = 0; ni < 2; ++ni) acc[mi][ni] = (f32x4)0.f;

  const int nt = K >> 6;

#define STAGE_FG(buf, t)                                                      \
  do {                                                                        \
    int k0_ = (t) << 6;                                                       \
    _Pragma("unroll")                                                         \
    for (int j = 0; j < 4; ++j) {                                             \
      int c = j * 4 + w;                                                      \
      int r = c * 8 + srow;                                                   \
      async_cp16(&A[(size_t)(m0 + r) * K + k0_ + ksrc], &As[buf][c * 512]);   \
    }                                                                         \
    _Pragma("unroll")                                                         \
    for (int j = 0; j < 2; ++j) {                                             \
      int c = j * 4 + w;                                                      \
      int gr = (c < 4) ? (n0 + c * 8 + srow)                                  \
                       : (FF + n0 + (c - 4) * 8 + srow);                      \
      async_cp16(&B[(size_t)gr * K + k0_ + ksrc], &Bs[buf][c * 512]);         \
    }                                                                         \
  } while (0)

#define COMPUTE_FG(buf)                                                       \
  do {                                                                        \
    _Pragma("unroll")                                                         \
    for (int ks = 0; ks < 2; ++ks) {                                          \
      bf16x8 af[4], bfr[2];                                                   \
      _Pragma("unroll")                                                       \
      for (int mi = 0; mi < 4; ++mi) {                                        \
        int r = wm + mi * 16 + lr;                                            \
        int boff = r * 128 + ((ks * 64 + kg * 16) ^ ((r & 7) << 4));          \
        af[mi] = *reinterpret_cast<const bf16x8*>(                            \
            reinterpret_cast<const char*>(As[buf]) + boff);                   \
      }                                                                       \
      _Pragma("unroll")                                                       \
      for (int ni = 0; ni < 2; ++ni) {                                        \
        int r = ni * 32 + wn2 + lr;                                           \
        int boff = r * 128 + ((ks * 64 + kg * 16) ^ ((r & 7) << 4));          \
        bfr[ni] = *reinterpret_cast<const bf16x8*>(                           \
            reinterpret_cast<const char*>(Bs[buf]) + boff);                   \
      }                                                                       \
      _Pragma("unroll")                                                       \
      for (int mi = 0; mi < 4; ++mi)                                          \
        _Pragma("unroll")                                                     \
        for (int ni = 0; ni < 2; ++ni)                                        \
          acc[mi][ni] = __builtin_amdgcn_mfma_f32_16x16x32_bf16(              \
              af[mi], bfr[ni], acc[mi][ni], 0, 0, 0);                         \
    }                                                                         \
  } while (0)

  STAGE_FG(0, 0);
  int cur = 0;
  for (int t = 0; t < nt; ++t) {
    if (t + 1 < nt) {
      STAGE_FG(cur ^ 1, t + 1);
      asm volatile("s_waitcnt vmcnt(6)" ::: "memory");
    } else {
      asm volatile("s_waitcnt vmcnt(0)" ::: "memory");
    }
    asm volatile("s_barrier" ::: "memory");
    COMPUTE_FG(cur);
    asm volatile("s_barrier" ::: "memory");
    cur ^= 1;
  }
#undef STAGE_FG
#undef COMPUTE_FG

  const int crow0 = (l >> 4) * 4;
  const int ccol = l & 15;
#pragma unroll
  for (int mi = 0; mi < 4; ++mi) {
    int col = n0 + wn2 + ccol;
    float ba = bias[col];
    float bg = bias[FF + col];
#pragma unroll
    for (int j = 0; j < 4; ++j) {
      int row = m0 + wm + mi * 16 + crow0 + j;
      float a = acc[mi][0][j] + ba;
      float g = acc[mi][1][j] + bg;
      float ge = 0.5f * g * (1.f + erff(g * 0.70710678118654752f));
      O[(size_t)row * FF + col] = f2bf(a * ge);
    }
  }
}

// ---------------- fp32 NT GEMM (dt_proj): bf16 out ----------------
__global__ __launch_bounds__(256) void gemm_nt(
    const float* __restrict__ A, int lda,
    const float* __restrict__ B, int ldb,
    ushort_t* __restrict__ Cb, int ldc,
    int N, int K,
    const float* __restrict__ bias, int act) {
  __shared__ __align__(16) float Asf[16][68];
  __shared__ __align__(16) float Bsf[16][68];
  const int tx = threadIdx.x;
  const int ty = threadIdx.y;
  const int tid = ty * 16 + tx;
  const int m0 = blockIdx.y * 64;
  const int n0 = blockIdx.x * 64;
  const int lrow = tid >> 2;
  const int lk = (tid & 3) * 4;

  float acc[4][4] = {{0.f}};

  for (int k0 = 0; k0 < K; k0 += 16) {
    float4 av, bv;
    {
      const float* ap = A + (size_t)(m0 + lrow) * lda + k0 + lk;
      av = *reinterpret_cast<const float4*>(ap);
    }
    int brow = n0 + lrow;
    if (brow < N) {
      const float* bp = B + (size_t)brow * ldb + k0 + lk;
      bv = *reinterpret_cast<const float4*>(bp);
    } else {
      bv = make_float4(0.f, 0.f, 0.f, 0.f);
    }
    __syncthreads();
    Asf[lk + 0][lrow] = av.x; Asf[lk + 1][lrow] = av.y;
    Asf[lk + 2][lrow] = av.z; Asf[lk + 3][lrow] = av.w;
    Bsf[lk + 0][lrow] = bv.x; Bsf[lk + 1][lrow] = bv.y;
    Bsf[lk + 2][lrow] = bv.z; Bsf[lk + 3][lrow] = bv.w;
    __syncthreads();
#pragma unroll
    for (int k = 0; k < 16; ++k) {
      const float4 a4 = *reinterpret_cast<const float4*>(&Asf[k][ty * 4]);
      const float4 b4 = *reinterpret_cast<const float4*>(&Bsf[k][tx * 4]);
      float a[4] = {a4.x, a4.y, a4.z, a4.w};
      float bb[4] = {b4.x, b4.y, b4.z, b4.w};
#pragma unroll
      for (int i = 0; i < 4; ++i)
#pragma unroll
        for (int j = 0; j < 4; ++j)
          acc[i][j] = fmaf(a[i], bb[j], acc[i][j]);
    }
  }

#pragma unroll
  for (int i = 0; i < 4; ++i) {
    int m = m0 + ty * 4 + i;
    int n = n0 + tx * 4;
    ushort4 ov;
    float v0 = acc[i][0], v1 = acc[i][1], v2 = acc[i][2], v3 = acc[i][3];
    if (bias) { v0 += bias[n]; v1 += bias[n + 1]; v2 += bias[n + 2]; v3 += bias[n + 3]; }
    if (act == 1) {
      v0 = (v0 > 20.f) ? v0 : log1pf(__expf(v0));
      v1 = (v1 > 20.f) ? v1 : log1pf(__expf(v1));
      v2 = (v2 > 20.f) ? v2 : log1pf(__expf(v2));
      v3 = (v3 > 20.f) ? v3 : log1pf(__expf(v3));
    }
    ov.x = f2bf(v0); ov.y = f2bf(v1); ov.z = f2bf(v2); ov.w = f2bf(v3);
    *reinterpret_cast<ushort4*>(Cb + (size_t)m * ldc + n) = ov;
  }
}

// ---------------- x_proj split-K stage 1 (bf16 activations) ----------------
__global__ __launch_bounds__(256) void xproj_partial(
    const ushort_t* __restrict__ A,   // xcb [4096, 2048] bf16
    const float* __restrict__ W,      // [96, 2048]
    float* __restrict__ pbuf) {       // [XP_KS, 4096, 96]
  __shared__ __align__(16) float As[64][68];
  __shared__ __align__(16) float Wsd[96][68];
  const int ks = blockIdx.x;
  const int mb = blockIdx.y;
  const int tid = threadIdx.x;
  const int r0 = (tid >> 4) * 4;        // 0..60
  const int c0 = (tid & 15) * 6;        // 0..90

  float acc[4][6];
#pragma unroll
  for (int i = 0; i < 4; ++i)
#pragma unroll
    for (int j = 0; j < 6; ++j) acc[i][j] = 0.f;

  for (int k0 = 0; k0 < XP_KSTEP; k0 += 64) {
    const int kbase = ks * XP_KSTEP + k0;
    __syncthreads();
    {
      int r = tid >> 2, c = (tid & 3) * 16;
      const ushort_t* src = A + (size_t)(mb * 64 + r) * D_INNER + kbase + c;
#pragma unroll
      for (int q = 0; q < 4; ++q) {
        ushort4 uv = *reinterpret_cast<const ushort4*>(src + q * 4);
        As[r][c + q * 4 + 0] = bf2f(uv.x);
        As[r][c + q * 4 + 1] = bf2f(uv.y);
        As[r][c + q * 4 + 2] = bf2f(uv.z);
        As[r][c + q * 4 + 3] = bf2f(uv.w);
      }
    }
#pragma unroll
    for (int q = 0; q < 6; ++q) {
      int f = q * 256 + tid;
      int wr = f >> 4;
      int wc = (f & 15) * 4;
      *reinterpret_cast<float4*>(&Wsd[wr][wc]) =
          *reinterpret_cast<const float4*>(&W[(size_t)wr * D_INNER + kbase + wc]);
    }
    __syncthreads();
#pragma unroll 16
    for (int k = 0; k < 64; ++k) {
      float a[4], wv[6];
#pragma unroll
      for (int i = 0; i < 4; ++i) a[i] = As[r0 + i][k];
#pragma unroll
      for (int j = 0; j < 6; ++j) wv[j] = Wsd[c0 + j][k];
#pragma unroll
      for (int i = 0; i < 4; ++i)
#pragma unroll
        for (int j = 0; j < 6; ++j)
          acc[i][j] = fmaf(a[i], wv[j], acc[i][j]);
    }
  }

  float* dst = pbuf + ((size_t)ks * ROWS + mb * 64) * 96;
#pragma unroll
  for (int i = 0; i < 4; ++i)
#pragma unroll
    for (int j = 0; j < 6; ++j)
      dst[(size_t)(r0 + i) * 96 + c0 + j] = acc[i][j];
}

// ---------------- x_proj split-K stage 2: reduce ----------------
__global__ __launch_bounds__(256) void xproj_reduce(
    const float* __restrict__ pbuf, float* __restrict__ xdbl) {
  int i = blockIdx.x * 256 + threadIdx.x;   // 0 .. ROWS*96-1
  float s = 0.f;
#pragma unroll
  for (int ks = 0; ks < XP_KS; ++ks)
    s += pbuf[(size_t)ks * (ROWS * 96) + i];
  xdbl[i] = s;
}

// ---------------- causal depthwise conv (k=4) + SiLU, bf16 in / bf16 out ----------------
__global__ __launch_bounds__(256) void conv_silu_kernel(
    const ushort_t* __restrict__ xzb, ushort_t* __restrict__ xcb,
    const float* __restrict__ cw, const float* __restrict__ cb) {
  int t = (blockIdx.x * 256 + threadIdx.x) * 4;
  if (t >= ROWS * D_INNER) return;
  int d = t & (D_INNER - 1);
  int row = t >> 11;
  int l = row & (SEQ - 1);
  float acc[4];
#pragma unroll
  for (int q = 0; q < 4; ++q) acc[q] = cb[d + q];
#pragma unroll
  for (int j = 0; j < 4; ++j) {
    int ls = l - 3 + j;
    if (ls >= 0) {
      ushort4 uv = *reinterpret_cast<const ushort4*>(
          xzb + (size_t)(row - 3 + j) * (2 * D_INNER) + d);
      acc[0] = fmaf(cw[(d + 0) * 4 + j], bf2f(uv.x), acc[0]);
      acc[1] = fmaf(cw[(d + 1) * 4 + j], bf2f(uv.y), acc[1]);
      acc[2] = fmaf(cw[(d + 2) * 4 + j], bf2f(uv.z), acc[2]);
      acc[3] = fmaf(cw[(d + 3) * 4 + j], bf2f(uv.w), acc[3]);
    }
  }
  ushort4 o;
  o.x = f2bf(acc[0] * sigmoidf_(acc[0]));
  o.y = f2bf(acc[1] * sigmoidf_(acc[1]));
  o.z = f2bf(acc[2] * sigmoidf_(acc[2]));
  o.w = f2bf(acc[3] * sigmoidf_(acc[3]));
  *reinterpret_cast<ushort4*>(xcb + t) = o;
}

// ================= chunked selective scan (CS=32, LDS B/C, 4-deep prefetch) =================
__global__ __launch_bounds__(256) void scan_pass1(
    const ushort_t* __restrict__ delta,   // bf16
    const ushort_t* __restrict__ xcb,
    const float* __restrict__ xdbl,
    const float* __restrict__ A_log,
    float* __restrict__ harr,
    float* __restrict__ dtsum) {
  __shared__ __align__(16) float Bls[CS][16];
  int gid = blockIdx.x * 256 + threadIdx.x;
  int d = gid & (D_INNER - 1);
  int bc = gid >> 11;
  int c = bc & (NC - 1);
  int b = bc >> NC_LOG;
  const size_t r0 = (size_t)b * SEQ + (size_t)c * CS;

  if (threadIdx.x < CS * 4) {
    int sl = threadIdx.x >> 2, sf = (threadIdx.x & 3) * 4;
    *reinterpret_cast<f32x4*>(&Bls[sl][sf]) =
        *reinterpret_cast<const f32x4*>(xdbl + (r0 + sl) * 96 + 64 + sf);
  }

  float Av2[D_STATE];
#pragma unroll
  for (int n = 0; n < D_STATE; ++n)
    Av2[n] = -__expf(A_log[(size_t)d * D_STATE + n]) * LOG2E;
  float h[D_STATE];
#pragma unroll
  for (int n = 0; n < D_STATE; ++n) h[n] = 0.f;
  float dts = 0.f;

  const ushort_t* drow = delta + r0 * D_INNER + d;
  const ushort_t* urow = xcb + r0 * D_INNER + d;

  float pdt[4], pu[4];
#pragma unroll
  for (int g = 0; g < 4; ++g) {
    pdt[g] = bf2f(drow[(size_t)g * D_INNER]);
    pu[g]  = bf2f(urow[(size_t)g * D_INNER]);
  }
  __syncthreads();

  for (int l0 = 0; l0 < CS; l0 += 4) {
    float cdt[4], cu[4];
#pragma unroll
    for (int g = 0; g < 4; ++g) { cdt[g] = pdt[g]; cu[g] = pu[g]; }
    if (l0 + 4 < CS) {
#pragma unroll
      for (int g = 0; g < 4; ++g) {
        pdt[g] = bf2f(drow[(size_t)(l0 + 4 + g) * D_INNER]);
        pu[g]  = bf2f(urow[(size_t)(l0 + 4 + g) * D_INNER]);
      }
    }
#pragma unroll
    for (int g = 0; g < 4; ++g) {
      int l = l0 + g;
      f32x4 B0 = *reinterpret_cast<const f32x4*>(&Bls[l][0]);
      f32x4 B1 = *reinterpret_cast<const f32x4*>(&Bls[l][4]);
      f32x4 B2 = *reinterpret_cast<const f32x4*>(&Bls[l][8]);
      f32x4 B3 = *reinterpret_cast<const f32x4*>(&Bls[l][12]);
      float du = cdt[g] * cu[g];
      dts += cdt[g];
      float Bsr[D_STATE] = {B0[0],B0[1],B0[2],B0[3], B1[0],B1[1],B1[2],B1[3],
                            B2[0],B2[1],B2[2],B2[3], B3[0],B3[1],B3[2],B3[3]};
#pragma unroll
      for (int n = 0; n < D_STATE; ++n) {
        float dA = __builtin_amdgcn_exp2f(cdt[g] * Av2[n]);
        h[n] = dA * h[n] + du * Bsr[n];
      }
    }
  }
#pragma unroll
  for (int n = 0; n < D_STATE; ++n)
    harr[((size_t)bc * D_STATE + n) * D_INNER + d] = h[n];
  dtsum[(size_t)bc * D_INNER + d] = dts;
}

// pass2: sequential combine over NC chunks; IN-PLACE: harr[c] := h0 for chunk c
__global__ __launch_bounds__(256) void scan_pass2(
    float* __restrict__ harr,
    const float* __restrict__ dtsum,
    const float* __restrict__ A_log) {
  int gid = blockIdx.x * 256 + threadIdx.x;
  int d = gid & (D_INNER - 1);
  int bn = gid >> 11;
  int n = bn & (D_STATE - 1);
  int b = bn >> 4;
  float Av2 = -__expf(A_log[(size_t)d * D_STATE + n]) * LOG2E;
  float h = 0.f;
  for (int c = 0; c < NC; ++c) {
    size_t bc = (size_t)b * NC + c;
    size_t idx = (bc * D_STATE + n) * D_INNER + d;
    float he = harr[idx];
    harr[idx] = h;
    float P = __builtin_amdgcn_exp2f(Av2 * dtsum[bc * D_INNER + d]);
    h = P * h + he;
  }
}

// pass3: rescan with true h0, y = h·C + u*D, gate silu(z) -> bf16
__global__ __launch_bounds__(256) void scan_pass3(
    const ushort_t* __restrict__ delta,   // bf16
    const ushort_t* __restrict__ xcb,
    ushort_t* __restrict__ ybf,
    const float* __restrict__ xdbl,
    const ushort_t* __restrict__ xzb,
    const float* __restrict__ A_log,
    const float* __restrict__ Dp,
    const float* __restrict__ harr) {
  __shared__ __align__(16) float BCls[CS][32];   // B at [0..16), C at [16..32)
  int gid = blockIdx.x * 256 + threadIdx.x;
  int d = gid & (D_INNER - 1);
  int bc = gid >> 11;
  int c = bc & (NC - 1);
  int b = bc >> NC_LOG;
  const size_t r0 = (size_t)b * SEQ + (size_t)c * CS;

  {
    int sl = threadIdx.x >> 3, sf = (threadIdx.x & 7) * 4;
    *reinterpret_cast<f32x4*>(&BCls[sl][sf]) =
        *reinterpret_cast<const f32x4*>(xdbl + (r0 + sl) * 96 + 64 + sf);
  }

  float Av2[D_STATE];
#pragma unroll
  for (int n = 0; n < D_STATE; ++n)
    Av2[n] = -__expf(A_log[(size_t)d * D_STATE + n]) * LOG2E;
  const float Dd = Dp[d];
  float h[D_STATE];
#pragma unroll
  for (int n = 0; n < D_STATE; ++n)
    h[n] = harr[((size_t)bc * D_STATE + n) * D_INNER + d];

  const ushort_t* drow = delta + r0 * D_INNER + d;
  const ushort_t* urow = xcb + r0 * D_INNER + d;
  const ushort_t* zrow = xzb + r0 * (2 * D_INNER) + D_INNER + d;
  ushort_t* yrow = ybf + r0 * D_INNER + d;

  float pdt[4], pu[4], pz[4];
#pragma unroll
  for (int g = 0; g < 4; ++g) {
    pdt[g] = bf2f(drow[(size_t)g * D_INNER]);
    pu[g]  = bf2f(urow[(size_t)g * D_INNER]);
    pz[g]  = bf2f(zrow[(size_t)g * (2 * D_INNER)]);
  }
  __syncthreads();

  for (int l0 = 0; l0 < CS; l0 += 4) {
    float cdt[4], cu[4], cz[4];
#pragma unroll
    for (int g = 0; g < 4; ++g) { cdt[g] = pdt[g]; cu[g] = pu[g]; cz[g] = pz[g]; }
    if (l0 + 4 < CS) {
#pragma unroll
      for (int g = 0; g < 4; ++g) {
        pdt[g] = bf2f(drow[(size_t)(l0 + 4 + g) * D_INNER]);
        pu[g]  = bf2f(urow[(size_t)(l0 + 4 + g) * D_INNER]);
        pz[g]  = bf2f(zrow[(size_t)(l0 + 4 + g) * (2 * D_INNER)]);
      }
    }
#pragma unroll
    for (int g = 0; g < 4; ++g) {
      int l = l0 + g;
      f32x4 B0 = *reinterpret_cast<const f32x4*>(&BCls[l][0]);
      f32x4 B1 = *reinterpret_cast<const f32x4*>(&BCls[l][4]);
      f32x4 B2 = *reinterpret_cast<const f32x4*>(&BCls[l][8]);
      f32x4 B3 = *reinterpret_cast<const f32x4*>(&BCls[l][12]);
      f32x4 C0 = *reinterpret_cast<const f32x4*>(&BCls[l][16]);
      f32x4 C1 = *reinterpret_cast<const f32x4*>(&BCls[l][20]);
      f32x4 C2 = *reinterpret_cast<const f32x4*>(&BCls[l][24]);
      f32x4 C3 = *reinterpret_cast<const f32x4*>(&BCls[l][28]);
      float du = cdt[g] * cu[g];
      float Bsr[D_STATE] = {B0[0],B0[1],B0[2],B0[3], B1[0],B1[1],B1[2],B1[3],
                            B2[0],B2[1],B2[2],B2[3], B3[0],B3[1],B3[2],B3[3]};
      float Csr[D_STATE] = {C0[0],C0[1],C0[2],C0[3], C1[0],C1[1],C1[2],C1[3],
                            C2[0],C2[1],C2[2],C2[3], C3[0],C3[1],C3[2],C3[3]};
      float y = 0.f;
#pragma unroll
      for (int n = 0; n < D_STATE; ++n) {
        float dA = __builtin_amdgcn_exp2f(cdt[g] * Av2[n]);
        h[n] = dA * h[n] + du * Bsr[n];
        y = fmaf(h[n], Csr[n], y);
      }
      y = fmaf(cu[g], Dd, y);
      yrow[(size_t)l * D_INNER] = f2bf(y * (cz[g] * sigmoidf_(cz[g])));
    }
  }
}

extern "C" void kernel_launch(void* const* d_in, const int* in_sizes, int n_in,
                              void* d_out, int out_size, void* d_ws, size_t ws_size,
                              hipStream_t stream) {
  const float* x         = (const float*)d_in[0];
  const float* in_proj_w = (const float*)d_in[1];
  const float* conv_w    = (const float*)d_in[2];
  const float* conv_b    = (const float*)d_in[3];
  const float* x_proj_w  = (const float*)d_in[4];
  const float* dt_proj_w = (const float*)d_in[5];
  const float* dt_proj_b = (const float*)d_in[6];
  const float* A_log     = (const float*)d_in[7];
  const float* Dp        = (const float*)d_in[8];
  const float* out_proj_w= (const float*)d_in[9];
  const float* rms_w     = (const float*)d_in[10];
  const float* ln_w      = (const float*)d_in[11];
  const float* ln_b      = (const float*)d_in[12];
  const float* ff_w1     = (const float*)d_in[13];
  const float* ff_b1     = (const float*)d_in[14];
  const float* ff_w2     = (const float*)d_in[15];
  const float* ff_b2     = (const float*)d_in[16];
  float* out = (float*)d_out;

  float* ws = (float*)d_ws;
  // ---- layout (float-word offsets); total end = 65,536,000 w = 250.0 MiB ----
  float* res     = ws;                              // [0, 4194304)
  float* dtsum   = ws + 4194304;                    // B*NC*D_INNER = 262,144 w
  float* xdbl    = ws + 8388608;                    // [8388608, 8781824)
  ushort_t* hbuf_bf = (ushort_t*)(ws + 8912896);    // 4M ushorts [8912896, 11010048)
  float*    pbuf    = ws + 11010048;                // x_proj partials 3.1M w
  ushort_t* y_bf    = (ushort_t*)(ws + 15204352);   // 8M ushorts [15204352, 19398656)
  ushort_t* glu_bf  = (ushort_t*)(ws + 11010048);   // overlays pbuf+y_bf (FFN phase)
  float* big   = ws + 19398656;                     // [19398656, 52953088)
  ushort_t* xz_bf = (ushort_t*)big;                 // 16.7M ushorts = 8,388,608 w (layer phase)
  ushort_t* xcb   = (ushort_t*)(big + 8388608);     // 8.4M ushorts = 4,194,304 w
  ushort_t* delta_bf = (ushort_t*)(big + 16777216); // 8.4M ushorts = 4,194,304 w (bf16 delta)
  float* harr  = big + 25165824;                    // B*NC*16*D_INNER = 4,194,304 w
  float* op_out= big;                               // 4M w (overlays xz_bf after scan)
  ushort_t* nrm_bf = (ushort_t*)(big + 16777216 + 4194304); // dead before dt_proj writes delta_bf
  ushort_t* in_w_bf  = (ushort_t*)(ws + 52953088);  // 8M ushorts [52953088, 57147392)
  ushort_t* out_w_bf = (ushort_t*)(ws + 57147392);  // 4M ushorts [57147392, 59244544)
  ushort_t* ff1_bf   = (ushort_t*)(ws + 59244544);  // 8M ushorts [59244544, 63438848)
  ushort_t* ff2_bf   = (ushort_t*)(ws + 63438848);  // 4M ushorts [63438848, 65536000)

  dim3 tb(16, 16);

  // all 4 weight conversions in one launch
  f2b_all<<<24576, 256, 0, stream>>>(in_proj_w, in_w_bf, out_proj_w, out_w_bf,
                                     ff_w1, ff1_bf, ff_w2, ff2_bf);

  // layer 0 input norm
  res_rms_kernel<<<ROWS, 256, 0, stream>>>(x, res, nrm_bf, rms_w);

  for (int i = 0; i < DEPTH; ++i) {
    const float* cw    = conv_w + (size_t)i * D_INNER * D_CONV;
    const float* cb    = conv_b + (size_t)i * D_INNER;
    const float* xp_w  = x_proj_w + (size_t)i * 96 * D_INNER;
    const float* dtp_w = dt_proj_w + (size_t)i * D_INNER * DT_RANK;
    const float* dtp_b = dt_proj_b + (size_t)i * D_INNER;
    const float* Alg   = A_log + (size_t)i * D_INNER * D_STATE;
    const float* Di    = Dp + (size_t)i * D_INNER;

    // in_proj: xz_bf[4096,4096] = nrm * in_w^T  (bf16 MFMA, dbuf+counted-vmcnt)
    gemm_bf16_nt<<<dim3(32, 32), 256, 0, stream>>>(
        nrm_bf, in_w_bf + (size_t)i * 4194304, nullptr, xz_bf, 2 * D_INNER, DIM,
        nullptr, 16);
    conv_silu_kernel<<<(ROWS * D_INNER / 4) / 256, 256, 0, stream>>>(xz_bf, xcb, cw, cb);
    // x_proj: split-K two-stage
    xproj_partial<<<dim3(XP_KS, 64), 256, 0, stream>>>(xcb, xp_w, pbuf);
    xproj_reduce<<<(ROWS * 96) / 256, 256, 0, stream>>>(pbuf, xdbl);
    // dt_proj + softplus -> bf16 delta
    gemm_nt<<<dim3(32, 64), tb, 0, stream>>>(xdbl, 96, dtp_w, DT_RANK, delta_bf,
                                             D_INNER, D_INNER, DT_RANK, dtp_b, 1);
    scan_pass1<<<(BATCH * NC * D_INNER) / 256, 256, 0, stream>>>(delta_bf, xcb, xdbl,
                                                                 Alg, harr, dtsum);
    scan_pass2<<<(BATCH * D_STATE * D_INNER) / 256, 256, 0, stream>>>(harr, dtsum, Alg);
    scan_pass3<<<(BATCH * NC * D_INNER) / 256, 256, 0, stream>>>(delta_bf, xcb, y_bf,
                                                                 xdbl, xz_bf, Alg, Di,
                                                                 harr);
    // out_proj: op_out[4096,1024] = y * o_w^T  (64x128 dbuf+counted-vmcnt); xz dead now
    gemm_bf16_nt64<<<dim3(8, 64), 256, 0, stream>>>(
        y_bf, out_w_bf + (size_t)i * 2097152, op_out, DIM, D_INNER, nullptr, 8);
    if (i + 1 < DEPTH) {
      ln_res_rms_kernel<<<ROWS, 256, 0, stream>>>(
          op_out, res, ln_w + (size_t)i * DIM, ln_b + (size_t)i * DIM,
          rms_w + (size_t)(i + 1) * DIM, nrm_bf);
    } else {
      ln_final_kernel<<<ROWS, 256, 0, stream>>>(
          op_out, hbuf_bf, ln_w + (size_t)i * DIM, ln_b + (size_t)i * DIM);
    }
  }

  // FFN1 + GEGLU fused (128x32-out tile, dbuf+vmcnt(6), grid 4096)
  gemm_ffn1_glu<<<dim3(128, 32), 256, 0, stream>>>(hbuf_bf, ff1_bf, glu_bf, DIM,
                                                   ff_b1, 16);
  // FFN2: out = glu * ff_w2^T + b2  (64x128 dbuf+counted-vmcnt)
  gemm_bf16_nt64<<<dim3(8, 64), 256, 0, stream>>>(glu_bf, ff2_bf, out, DIM, FF,
                                                  ff_b2, 8);
}

// Round 20
// 737.121 us; speedup vs baseline: 1.0151x; 1.0151x over previous
//
#include <hip/hip_runtime.h>
#include <cstdint>
#include <cstddef>

#define DIM     1024
#define SEQ     2048
#define BATCH   2
#define DEPTH   2
#define D_INNER 2048
#define D_STATE 16
#define D_CONV  4
#define DT_RANK 64
#define FF      4096
#define ROWS    (BATCH*SEQ)   // 4096
#define EPS     1e-5f

#define CS      32            // scan chunk size
#define NC      (SEQ/CS)      // 64 chunks
#define NC_LOG  6

#define XP_KS    8            // x_proj k-split
#define XP_KSTEP (D_INNER/XP_KS)  // 256

#define LOG2E 1.44269504088896f

typedef unsigned short ushort_t;
typedef short bf16x8 __attribute__((ext_vector_type(8)));
typedef float f32x4  __attribute__((ext_vector_type(4)));

__device__ __forceinline__ float sigmoidf_(float x) { return 1.f / (1.f + __expf(-x)); }

// bf16 <-> fp32
__device__ __forceinline__ ushort_t f2bf(float x) {
  unsigned int u = __float_as_uint(x);
  u += 0x7fffu + ((u >> 16) & 1u);
  return (ushort_t)(u >> 16);
}
__device__ __forceinline__ float bf2f(ushort_t u) {
  return __uint_as_float((unsigned)u << 16);
}

// async global->LDS 16B (wave-uniform LDS base + lane*16)
__device__ __forceinline__ void async_cp16(const void* g, void* lds) {
  __builtin_amdgcn_global_load_lds(
      (const __attribute__((address_space(1))) unsigned int*)g,
      (__attribute__((address_space(3))) unsigned int*)lds, 16, 0, 0);
}

// ---------------- block-wide reduction ----------------
__device__ __forceinline__ float2 block_sum2(float a, float b) {
#pragma unroll
  for (int off = 32; off > 0; off >>= 1) {
    a += __shfl_down(a, off, 64);
    b += __shfl_down(b, off, 64);
  }
  __shared__ float sa[4], sb[4];
  __syncthreads();
  if ((threadIdx.x & 63) == 0) { int w = threadIdx.x >> 6; sa[w] = a; sb[w] = b; }
  __syncthreads();
  return make_float2(sa[0] + sa[1] + sa[2] + sa[3], sb[0] + sb[1] + sb[2] + sb[3]);
}

// ---------------- residual add + RMSNorm (bf16 normed out) ----------------
__global__ __launch_bounds__(256) void res_rms_kernel(
    const float* __restrict__ xin,
    float* __restrict__ res, ushort_t* __restrict__ nrm, const float* __restrict__ w) {
  int row = blockIdx.x;
  const float* xr = xin + (size_t)row * DIM;
  float* rr = res + (size_t)row * DIM;
  ushort_t* nr = nrm + (size_t)row * DIM;
  float v[4]; float ss = 0.f;
#pragma unroll
  for (int i = 0; i < 4; ++i) {
    int j = threadIdx.x + i * 256;
    float t = xr[j];
    v[i] = t; rr[j] = t; ss += t * t;
  }
  float2 s = block_sum2(ss, 0.f);
  float rstd = rsqrtf(s.x * (1.f / DIM) + EPS);
#pragma unroll
  for (int i = 0; i < 4; ++i) {
    int j = threadIdx.x + i * 256;
    nr[j] = f2bf(v[i] * rstd * w[j]);
  }
}

// ---------------- fused LayerNorm -> residual add -> RMSNorm (bf16 out) ----------------
__global__ __launch_bounds__(256) void ln_res_rms_kernel(
    const float* __restrict__ in, float* __restrict__ res,
    const float* __restrict__ lw, const float* __restrict__ lb,
    const float* __restrict__ rw, ushort_t* __restrict__ nrm) {
  int row = blockIdx.x;
  const float* xr = in + (size_t)row * DIM;
  float* rr = res + (size_t)row * DIM;
  ushort_t* nr = nrm + (size_t)row * DIM;
  float v[4]; float s1 = 0.f, s2 = 0.f;
#pragma unroll
  for (int i = 0; i < 4; ++i) {
    int j = threadIdx.x + i * 256;
    float t = xr[j];
    v[i] = t; s1 += t; s2 += t * t;
  }
  float2 s = block_sum2(s1, s2);
  float mean = s.x * (1.f / DIM);
  float var = s.y * (1.f / DIM) - mean * mean;
  float rstd = rsqrtf(var + EPS);
  float t4[4]; float ss = 0.f;
#pragma unroll
  for (int i = 0; i < 4; ++i) {
    int j = threadIdx.x + i * 256;
    float o = (v[i] - mean) * rstd * lw[j] + lb[j];
    float t = rr[j] + o;
    rr[j] = t;
    t4[i] = t; ss += t * t;
  }
  float2 s2v = block_sum2(ss, 0.f);
  float rstd2 = rsqrtf(s2v.x * (1.f / DIM) + EPS);
#pragma unroll
  for (int i = 0; i < 4; ++i) {
    int j = threadIdx.x + i * 256;
    nr[j] = f2bf(t4[i] * rstd2 * rw[j]);
  }
}

// ---------------- final LayerNorm (bf16 out only) ----------------
__global__ __launch_bounds__(256) void ln_final_kernel(
    const float* __restrict__ in, ushort_t* __restrict__ outb,
    const float* __restrict__ w, const float* __restrict__ b) {
  int row = blockIdx.x;
  const float* xr = in + (size_t)row * DIM;
  ushort_t* obrow = outb + (size_t)row * DIM;
  float v[4]; float s1 = 0.f, s2 = 0.f;
#pragma unroll
  for (int i = 0; i < 4; ++i) {
    int j = threadIdx.x + i * 256;
    float t = xr[j];
    v[i] = t; s1 += t; s2 += t * t;
  }
  float2 s = block_sum2(s1, s2);
  float mean = s.x * (1.f / DIM);
  float var = s.y * (1.f / DIM) - mean * mean;
  float rstd = rsqrtf(var + EPS);
#pragma unroll
  for (int i = 0; i < 4; ++i) {
    int j = threadIdx.x + i * 256;
    obrow[j] = f2bf((v[i] - mean) * rstd * w[j] + b[j]);
  }
}

// ---------------- fused fp32 -> bf16 conversion for all 4 weight tensors ----------------
__global__ __launch_bounds__(256) void f2b_all(
    const float* __restrict__ w0, ushort_t* __restrict__ d0,
    const float* __restrict__ w1, ushort_t* __restrict__ d1,
    const float* __restrict__ w2, ushort_t* __restrict__ d2,
    const float* __restrict__ w3, ushort_t* __restrict__ d3) {
  int i = (blockIdx.x * 256 + threadIdx.x) * 4;
  const float* s; ushort_t* d; int off;
  if (i < 8388608)        { s = w0; d = d0; off = i; }
  else if (i < 12582912)  { s = w1; d = d1; off = i - 8388608; }
  else if (i < 20971520)  { s = w2; d = d2; off = i - 12582912; }
  else                    { s = w3; d = d3; off = i - 20971520; }
  float4 v = *reinterpret_cast<const float4*>(s + off);
  d[off + 0] = f2bf(v.x); d[off + 1] = f2bf(v.y);
  d[off + 2] = f2bf(v.z); d[off + 3] = f2bf(v.w);
}

// ---------------- bf16 MFMA NT GEMM: C = A[M,K] * B[N,K]^T (+bias) ----------------
// 128x128 tile, BK=64, 4 waves (2x2), 16x16x32 MFMA.
// DOUBLE-BUFFERED LDS + counted vmcnt (helps K-deep in_proj; kept per R15/16 A/B).
__global__ __launch_bounds__(256) void gemm_bf16_nt(
    const ushort_t* __restrict__ A,
    const ushort_t* __restrict__ B,
    float* __restrict__ C,
    ushort_t* __restrict__ Cb,
    int N, int K,
    const float* __restrict__ bias, int grp) {
  __shared__ ushort_t As[2][128 * 64];
  __shared__ ushort_t Bs[2][128 * 64];
  const int tid = threadIdx.x;
  const int l = tid & 63;
  const int w = tid >> 6;

  const unsigned nwgx = gridDim.x;
  const unsigned nwg = nwgx * gridDim.y;
  const unsigned bid = blockIdx.y * nwgx + blockIdx.x;
  const unsigned cpx = nwg >> 3;
  const unsigned s = (bid & 7u) * cpx + (bid >> 3);
  const unsigned bandw = (unsigned)grp * nwgx;
  const unsigned band = s / bandw;
  const unsigned rem = s % bandw;
  const int m0 = (int)(band * grp + (rem % grp)) * 128;
  const int n0 = (int)(rem / grp) * 128;

  const int wm = (w >> 1) * 64;
  const int wn = (w & 1) * 64;

  const int srow = l >> 3;                      // 0..7 (row within 8-row chunk)
  const int ksrc = 8 * ((l & 7) ^ srow);        // swizzled source k-offset (elements)
  const int kg = l >> 4;                        // 0..3
  const int lr = l & 15;

  f32x4 acc[4][4];
#pragma unroll
  for (int mi = 0; mi < 4; ++mi)
#pragma unroll
    for (int ni = 0; ni < 4; ++ni) acc[mi][ni] = (f32x4)0.f;

  const int nt = K >> 6;

#define STAGE_NT(buf, t)                                                      \
  do {                                                                        \
    int k0_ = (t) << 6;                                                       \
    _Pragma("unroll")                                                         \
    for (int j = 0; j < 4; ++j) {                                             \
      int c = j * 4 + w;                                                      \
      int r = c * 8 + srow;                                                   \
      async_cp16(&A[(size_t)(m0 + r) * K + k0_ + ksrc], &As[buf][c * 512]);   \
    }                                                                         \
    _Pragma("unroll")                                                         \
    for (int j = 0; j < 4; ++j) {                                             \
      int c = j * 4 + w;                                                      \
      int r = c * 8 + srow;                                                   \
      async_cp16(&B[(size_t)(n0 + r) * K + k0_ + ksrc], &Bs[buf][c * 512]);   \
    }                                                                         \
  } while (0)

#define COMPUTE_NT(buf)                                                       \
  do {                                                                        \
    _Pragma("unroll")                                                         \
    for (int ks = 0; ks < 2; ++ks) {                                          \
      bf16x8 af[4], bfr[4];                                                   \
      _Pragma("unroll")                                                       \
      for (int mi = 0; mi < 4; ++mi) {                                        \
        int r = wm + mi * 16 + lr;                                            \
        int boff = r * 128 + ((ks * 64 + kg * 16) ^ ((r & 7) << 4));          \
        af[mi] = *reinterpret_cast<const bf16x8*>(                            \
            reinterpret_cast<const char*>(As[buf]) + boff);                   \
      }                                                                       \
      _Pragma("unroll")                                                       \
      for (int ni = 0; ni < 4; ++ni) {                                        \
        int r = wn + ni * 16 + lr;                                            \
        int boff = r * 128 + ((ks * 64 + kg * 16) ^ ((r & 7) << 4));          \
        bfr[ni] = *reinterpret_cast<const bf16x8*>(                           \
            reinterpret_cast<const char*>(Bs[buf]) + boff);                   \
      }                                                                       \
      _Pragma("unroll")                                                       \
      for (int mi = 0; mi < 4; ++mi)                                          \
        _Pragma("unroll")                                                     \
        for (int ni = 0; ni < 4; ++ni)                                        \
          acc[mi][ni] = __builtin_amdgcn_mfma_f32_16x16x32_bf16(              \
              af[mi], bfr[ni], acc[mi][ni], 0, 0, 0);                         \
    }                                                                         \
  } while (0)

  STAGE_NT(0, 0);
  int cur = 0;
  for (int t = 0; t < nt; ++t) {
    if (t + 1 < nt) {
      STAGE_NT(cur ^ 1, t + 1);
      asm volatile("s_waitcnt vmcnt(8)" ::: "memory");
    } else {
      asm volatile("s_waitcnt vmcnt(0)" ::: "memory");
    }
    asm volatile("s_barrier" ::: "memory");
    COMPUTE_NT(cur);
    asm volatile("s_barrier" ::: "memory");
    cur ^= 1;
  }
#undef STAGE_NT
#undef COMPUTE_NT

  const int crow0 = (l >> 4) * 4;
  const int ccol = l & 15;
#pragma unroll
  for (int mi = 0; mi < 4; ++mi) {
#pragma unroll
    for (int ni = 0; ni < 4; ++ni) {
      int col = n0 + wn + ni * 16 + ccol;
      float bv = bias ? bias[col] : 0.f;
#pragma unroll
      for (int j = 0; j < 4; ++j) {
        int row = m0 + wm + mi * 16 + crow0 + j;
        float v = acc[mi][ni][j] + bv;
        if (Cb) Cb[(size_t)row * N + col] = f2bf(v);
        else    C[(size_t)row * N + col] = v;
      }
    }
  }
}

// ---------------- bf16 MFMA NT GEMM, 64x128 tile (for N=1024 GEMMs) ----------------
// DOUBLE-BUFFERED + counted vmcnt(6): deep-K, grid-limited to 2 blocks/CU.
__global__ __launch_bounds__(256) void gemm_bf16_nt64(
    const ushort_t* __restrict__ A,
    const ushort_t* __restrict__ B,
    float* __restrict__ C,
    int N, int K,
    const float* __restrict__ bias, int grp) {
  __shared__ ushort_t As[2][64 * 64];
  __shared__ ushort_t Bs[2][128 * 64];
  const int tid = threadIdx.x;
  const int l = tid & 63;
  const int w = tid >> 6;

  const unsigned nwgx = gridDim.x;
  const unsigned nwg = nwgx * gridDim.y;
  const unsigned bid = blockIdx.y * nwgx + blockIdx.x;
  const unsigned cpx = nwg >> 3;
  const unsigned s = (bid & 7u) * cpx + (bid >> 3);
  const unsigned bandw = (unsigned)grp * nwgx;
  const unsigned band = s / bandw;
  const unsigned rem = s % bandw;
  const int m0 = (int)(band * grp + (rem % grp)) * 64;
  const int n0 = (int)(rem / grp) * 128;

  const int wm = (w >> 1) * 32;
  const int wn = (w & 1) * 64;

  const int srow = l >> 3;
  const int ksrc = 8 * ((l & 7) ^ srow);
  const int kg = l >> 4;
  const int lr = l & 15;

  f32x4 acc[2][4];
#pragma unroll
  for (int mi = 0; mi < 2; ++mi)
#pragma unroll
    for (int ni = 0; ni < 4; ++ni) acc[mi][ni] = (f32x4)0.f;

  const int nt = K >> 6;

#define STAGE_64(buf, t)                                                      \
  do {                                                                        \
    int k0_ = (t) << 6;                                                       \
    _Pragma("unroll")                                                         \
    for (int j = 0; j < 2; ++j) {                                             \
      int c = j * 4 + w;                                                      \
      int r = c * 8 + srow;                                                   \
      async_cp16(&A[(size_t)(m0 + r) * K + k0_ + ksrc], &As[buf][c * 512]);   \
    }                                                                         \
    _Pragma("unroll")                                                         \
    for (int j = 0; j < 4; ++j) {                                             \
      int c = j * 4 + w;                                                      \
      int r = c * 8 + srow;                                                   \
      async_cp16(&B[(size_t)(n0 + r) * K + k0_ + ksrc], &Bs[buf][c * 512]);   \
    }                                                                         \
  } while (0)

#define COMPUTE_64(buf)                                                       \
  do {                                                                        \
    _Pragma("unroll")                                                         \
    for (int ks = 0; ks < 2; ++ks) {                                          \
      bf16x8 af[2], bfr[4];                                                   \
      _Pragma("unroll")                                                       \
      for (int mi = 0; mi < 2; ++mi) {                                        \
        int r = wm + mi * 16 + lr;                                            \
        int boff = r * 128 + ((ks * 64 + kg * 16) ^ ((r & 7) << 4));          \
        af[mi] = *reinterpret_cast<const bf16x8*>(                            \
            reinterpret_cast<const char*>(As[buf]) + boff);                   \
      }                                                                       \
      _Pragma("unroll")                                                       \
      for (int ni = 0; ni < 4; ++ni) {                                        \
        int r = wn + ni * 16 + lr;                                            \
        int boff = r * 128 + ((ks * 64 + kg * 16) ^ ((r & 7) << 4));          \
        bfr[ni] = *reinterpret_cast<const bf16x8*>(                           \
            reinterpret_cast<const char*>(Bs[buf]) + boff);                   \
      }                                                                       \
      _Pragma("unroll")                                                       \
      for (int mi = 0; mi < 2; ++mi)                                          \
        _Pragma("unroll")                                                     \
        for (int ni = 0; ni < 4; ++ni)                                        \
          acc[mi][ni] = __builtin_amdgcn_mfma_f32_16x16x32_bf16(              \
              af[mi], bfr[ni], acc[mi][ni], 0, 0, 0);                         \
    }                                                                         \
  } while (0)

  STAGE_64(0, 0);
  int cur = 0;
  for (int t = 0; t < nt; ++t) {
    if (t + 1 < nt) {
      STAGE_64(cur ^ 1, t + 1);
      asm volatile("s_waitcnt vmcnt(6)" ::: "memory");
    } else {
      asm volatile("s_waitcnt vmcnt(0)" ::: "memory");
    }
    asm volatile("s_barrier" ::: "memory");
    COMPUTE_64(cur);
    asm volatile("s_barrier" ::: "memory");
    cur ^= 1;
  }
#undef STAGE_64
#undef COMPUTE_64

  const int crow0 = (l >> 4) * 4;
  const int ccol = l & 15;
#pragma unroll
  for (int mi = 0; mi < 2; ++mi) {
#pragma unroll
    for (int ni = 0; ni < 4; ++ni) {
      int col = n0 + wn + ni * 16 + ccol;
      float bv = bias ? bias[col] : 0.f;
#pragma unroll
      for (int j = 0; j < 4; ++j) {
        int row = m0 + wm + mi * 16 + crow0 + j;
        C[(size_t)row * N + col] = acc[mi][ni][j] + bv;
      }
    }
  }
}

// ---------------- fused FFN1 + GEGLU: glu = a * gelu(g), bf16 out ----------------
// Single-buffer LDS, 128x64-out tile (R16/R18 best: ~91us; R15 dbuf and R19
// narrow-tile variants both regress it).
__global__ __launch_bounds__(256) void gemm_ffn1_glu(
    const ushort_t* __restrict__ A,
    const ushort_t* __restrict__ B,
    ushort_t* __restrict__ O,
    int K,
    const float* __restrict__ bias, int grp) {
  __shared__ ushort_t As[128 * 64];
  __shared__ ushort_t Bs[128 * 64];
  const int tid = threadIdx.x;
  const int l = tid & 63;
  const int w = tid >> 6;

  const unsigned nwgx = gridDim.x;                // 64 col-panels of width 64
  const unsigned nwg = nwgx * gridDim.y;
  const unsigned bid = blockIdx.y * nwgx + blockIdx.x;
  const unsigned cpx = nwg >> 3;
  const unsigned s = (bid & 7u) * cpx + (bid >> 3);
  const unsigned bandw = (unsigned)grp * nwgx;
  const unsigned band = s / bandw;
  const unsigned rem = s % bandw;
  const int m0 = (int)(band * grp + (rem % grp)) * 128;
  const int n0 = (int)(rem / grp) * 64;

  const int wm = (w >> 1) * 64;
  const int wn2 = (w & 1) * 32;

  const int srow = l >> 3;
  const int ksrc = 8 * ((l & 7) ^ srow);
  const int kg = l >> 4;
  const int lr = l & 15;

  f32x4 acc[4][4];
#pragma unroll
  for (int mi = 0; mi < 4; ++mi)
#pragma unroll
    for (int ni = 0; ni < 4; ++ni) acc[mi][ni] = (f32x4)0.f;

  for (int k0 = 0; k0 < K; k0 += 64) {
#pragma unroll
    for (int j = 0; j < 4; ++j) {
      int c = j * 4 + w;
      int r = c * 8 + srow;
      async_cp16(&A[(size_t)(m0 + r) * K + k0 + ksrc], &As[c * 512]);
    }
#pragma unroll
    for (int j = 0; j < 4; ++j) {
      int c = j * 4 + w;
      int gr = (c < 8) ? (n0 + c * 8 + srow)
                       : (FF + n0 + (c - 8) * 8 + srow);
      async_cp16(&B[(size_t)gr * K + k0 + ksrc], &Bs[c * 512]);
    }
    __syncthreads();
#pragma unroll
    for (int ks = 0; ks < 2; ++ks) {
      bf16x8 af[4], bfr[4];
#pragma unroll
      for (int mi = 0; mi < 4; ++mi) {
        int r = wm + mi * 16 + lr;
        int boff = r * 128 + ((ks * 64 + kg * 16) ^ ((r & 7) << 4));
        af[mi] = *reinterpret_cast<const bf16x8*>(reinterpret_cast<const char*>(As) + boff);
      }
#pragma unroll
      for (int ni = 0; ni < 4; ++ni) {
        int r = (ni < 2 ? wn2 + ni * 16 : 64 + wn2 + (ni - 2) * 16) + lr;
        int boff = r * 128 + ((ks * 64 + kg * 16) ^ ((r & 7) << 4));
        bfr[ni] = *reinterpret_cast<const bf16x8*>(reinterpret_cast<const char*>(Bs) + boff);
      }
#pragma unroll
      for (int mi = 0; mi < 4; ++mi)
#pragma unroll
        for (int ni = 0; ni < 4; ++ni)
          acc[mi][ni] = __builtin_amdgcn_mfma_f32_16x16x32_bf16(af[mi], bfr[ni], acc[mi][ni], 0, 0, 0);
    }
    __syncthreads();
  }

  const int crow0 = (l >> 4) * 4;
  const int ccol = l & 15;
#pragma unroll
  for (int mi = 0; mi < 4; ++mi) {
#pragma unroll
    for (int ni = 0; ni < 2; ++ni) {
      int col = n0 + wn2 + ni * 16 + ccol;
      float ba = bias[col];
      float bg = bias[FF + col];
#pragma unroll
      for (int j = 0; j < 4; ++j) {
        int row = m0 + wm + mi * 16 + crow0 + j;
        float a = acc[mi][ni][j] + ba;
        float g = acc[mi][ni + 2][j] + bg;
        float ge = 0.5f * g * (1.f + erff(g * 0.70710678118654752f));
        O[(size_t)row * FF + col] = f2bf(a * ge);
      }
    }
  }
}

// ---------------- fp32 NT GEMM (dt_proj): bf16 out ----------------
__global__ __launch_bounds__(256) void gemm_nt(
    const float* __restrict__ A, int lda,
    const float* __restrict__ B, int ldb,
    ushort_t* __restrict__ Cb, int ldc,
    int N, int K,
    const float* __restrict__ bias, int act) {
  __shared__ __align__(16) float Asf[16][68];
  __shared__ __align__(16) float Bsf[16][68];
  const int tx = threadIdx.x;
  const int ty = threadIdx.y;
  const int tid = ty * 16 + tx;
  const int m0 = blockIdx.y * 64;
  const int n0 = blockIdx.x * 64;
  const int lrow = tid >> 2;
  const int lk = (tid & 3) * 4;

  float acc[4][4] = {{0.f}};

  for (int k0 = 0; k0 < K; k0 += 16) {
    float4 av, bv;
    {
      const float* ap = A + (size_t)(m0 + lrow) * lda + k0 + lk;
      av = *reinterpret_cast<const float4*>(ap);
    }
    int brow = n0 + lrow;
    if (brow < N) {
      const float* bp = B + (size_t)brow * ldb + k0 + lk;
      bv = *reinterpret_cast<const float4*>(bp);
    } else {
      bv = make_float4(0.f, 0.f, 0.f, 0.f);
    }
    __syncthreads();
    Asf[lk + 0][lrow] = av.x; Asf[lk + 1][lrow] = av.y;
    Asf[lk + 2][lrow] = av.z; Asf[lk + 3][lrow] = av.w;
    Bsf[lk + 0][lrow] = bv.x; Bsf[lk + 1][lrow] = bv.y;
    Bsf[lk + 2][lrow] = bv.z; Bsf[lk + 3][lrow] = bv.w;
    __syncthreads();
#pragma unroll
    for (int k = 0; k < 16; ++k) {
      const float4 a4 = *reinterpret_cast<const float4*>(&Asf[k][ty * 4]);
      const float4 b4 = *reinterpret_cast<const float4*>(&Bsf[k][tx * 4]);
      float a[4] = {a4.x, a4.y, a4.z, a4.w};
      float bb[4] = {b4.x, b4.y, b4.z, b4.w};
#pragma unroll
      for (int i = 0; i < 4; ++i)
#pragma unroll
        for (int j = 0; j < 4; ++j)
          acc[i][j] = fmaf(a[i], bb[j], acc[i][j]);
    }
  }

#pragma unroll
  for (int i = 0; i < 4; ++i) {
    int m = m0 + ty * 4 + i;
    int n = n0 + tx * 4;
    ushort4 ov;
    float v0 = acc[i][0], v1 = acc[i][1], v2 = acc[i][2], v3 = acc[i][3];
    if (bias) { v0 += bias[n]; v1 += bias[n + 1]; v2 += bias[n + 2]; v3 += bias[n + 3]; }
    if (act == 1) {
      v0 = (v0 > 20.f) ? v0 : log1pf(__expf(v0));
      v1 = (v1 > 20.f) ? v1 : log1pf(__expf(v1));
      v2 = (v2 > 20.f) ? v2 : log1pf(__expf(v2));
      v3 = (v3 > 20.f) ? v3 : log1pf(__expf(v3));
    }
    ov.x = f2bf(v0); ov.y = f2bf(v1); ov.z = f2bf(v2); ov.w = f2bf(v3);
    *reinterpret_cast<ushort4*>(Cb + (size_t)m * ldc + n) = ov;
  }
}

// ---------------- x_proj split-K stage 1 (bf16 activations) ----------------
__global__ __launch_bounds__(256) void xproj_partial(
    const ushort_t* __restrict__ A,   // xcb [4096, 2048] bf16
    const float* __restrict__ W,      // [96, 2048]
    float* __restrict__ pbuf) {       // [XP_KS, 4096, 96]
  __shared__ __align__(16) float As[64][68];
  __shared__ __align__(16) float Wsd[96][68];
  const int ks = blockIdx.x;
  const int mb = blockIdx.y;
  const int tid = threadIdx.x;
  const int r0 = (tid >> 4) * 4;        // 0..60
  const int c0 = (tid & 15) * 6;        // 0..90

  float acc[4][6];
#pragma unroll
  for (int i = 0; i < 4; ++i)
#pragma unroll
    for (int j = 0; j < 6; ++j) acc[i][j] = 0.f;

  for (int k0 = 0; k0 < XP_KSTEP; k0 += 64) {
    const int kbase = ks * XP_KSTEP + k0;
    __syncthreads();
    {
      int r = tid >> 2, c = (tid & 3) * 16;
      const ushort_t* src = A + (size_t)(mb * 64 + r) * D_INNER + kbase + c;
#pragma unroll
      for (int q = 0; q < 4; ++q) {
        ushort4 uv = *reinterpret_cast<const ushort4*>(src + q * 4);
        As[r][c + q * 4 + 0] = bf2f(uv.x);
        As[r][c + q * 4 + 1] = bf2f(uv.y);
        As[r][c + q * 4 + 2] = bf2f(uv.z);
        As[r][c + q * 4 + 3] = bf2f(uv.w);
      }
    }
#pragma unroll
    for (int q = 0; q < 6; ++q) {
      int f = q * 256 + tid;
      int wr = f >> 4;
      int wc = (f & 15) * 4;
      *reinterpret_cast<float4*>(&Wsd[wr][wc]) =
          *reinterpret_cast<const float4*>(&W[(size_t)wr * D_INNER + kbase + wc]);
    }
    __syncthreads();
#pragma unroll 16
    for (int k = 0; k < 64; ++k) {
      float a[4], wv[6];
#pragma unroll
      for (int i = 0; i < 4; ++i) a[i] = As[r0 + i][k];
#pragma unroll
      for (int j = 0; j < 6; ++j) wv[j] = Wsd[c0 + j][k];
#pragma unroll
      for (int i = 0; i < 4; ++i)
#pragma unroll
        for (int j = 0; j < 6; ++j)
          acc[i][j] = fmaf(a[i], wv[j], acc[i][j]);
    }
  }

  float* dst = pbuf + ((size_t)ks * ROWS + mb * 64) * 96;
#pragma unroll
  for (int i = 0; i < 4; ++i)
#pragma unroll
    for (int j = 0; j < 6; ++j)
      dst[(size_t)(r0 + i) * 96 + c0 + j] = acc[i][j];
}

// ---------------- x_proj split-K stage 2: reduce ----------------
__global__ __launch_bounds__(256) void xproj_reduce(
    const float* __restrict__ pbuf, float* __restrict__ xdbl) {
  int i = blockIdx.x * 256 + threadIdx.x;   // 0 .. ROWS*96-1
  float s = 0.f;
#pragma unroll
  for (int ks = 0; ks < XP_KS; ++ks)
    s += pbuf[(size_t)ks * (ROWS * 96) + i];
  xdbl[i] = s;
}

// ---------------- causal depthwise conv (k=4) + SiLU, bf16 in / bf16 out ----------------
__global__ __launch_bounds__(256) void conv_silu_kernel(
    const ushort_t* __restrict__ xzb, ushort_t* __restrict__ xcb,
    const float* __restrict__ cw, const float* __restrict__ cb) {
  int t = (blockIdx.x * 256 + threadIdx.x) * 4;
  if (t >= ROWS * D_INNER) return;
  int d = t & (D_INNER - 1);
  int row = t >> 11;
  int l = row & (SEQ - 1);
  float acc[4];
#pragma unroll
  for (int q = 0; q < 4; ++q) acc[q] = cb[d + q];
#pragma unroll
  for (int j = 0; j < 4; ++j) {
    int ls = l - 3 + j;
    if (ls >= 0) {
      ushort4 uv = *reinterpret_cast<const ushort4*>(
          xzb + (size_t)(row - 3 + j) * (2 * D_INNER) + d);
      acc[0] = fmaf(cw[(d + 0) * 4 + j], bf2f(uv.x), acc[0]);
      acc[1] = fmaf(cw[(d + 1) * 4 + j], bf2f(uv.y), acc[1]);
      acc[2] = fmaf(cw[(d + 2) * 4 + j], bf2f(uv.z), acc[2]);
      acc[3] = fmaf(cw[(d + 3) * 4 + j], bf2f(uv.w), acc[3]);
    }
  }
  ushort4 o;
  o.x = f2bf(acc[0] * sigmoidf_(acc[0]));
  o.y = f2bf(acc[1] * sigmoidf_(acc[1]));
  o.z = f2bf(acc[2] * sigmoidf_(acc[2]));
  o.w = f2bf(acc[3] * sigmoidf_(acc[3]));
  *reinterpret_cast<ushort4*>(xcb + t) = o;
}

// ================= chunked selective scan (CS=32, LDS B/C, 4-deep prefetch) =================
__global__ __launch_bounds__(256) void scan_pass1(
    const ushort_t* __restrict__ delta,   // bf16
    const ushort_t* __restrict__ xcb,
    const float* __restrict__ xdbl,
    const float* __restrict__ A_log,
    float* __restrict__ harr,
    float* __restrict__ dtsum) {
  __shared__ __align__(16) float Bls[CS][16];
  int gid = blockIdx.x * 256 + threadIdx.x;
  int d = gid & (D_INNER - 1);
  int bc = gid >> 11;
  int c = bc & (NC - 1);
  int b = bc >> NC_LOG;
  const size_t r0 = (size_t)b * SEQ + (size_t)c * CS;

  if (threadIdx.x < CS * 4) {
    int sl = threadIdx.x >> 2, sf = (threadIdx.x & 3) * 4;
    *reinterpret_cast<f32x4*>(&Bls[sl][sf]) =
        *reinterpret_cast<const f32x4*>(xdbl + (r0 + sl) * 96 + 64 + sf);
  }

  float Av2[D_STATE];
#pragma unroll
  for (int n = 0; n < D_STATE; ++n)
    Av2[n] = -__expf(A_log[(size_t)d * D_STATE + n]) * LOG2E;
  float h[D_STATE];
#pragma unroll
  for (int n = 0; n < D_STATE; ++n) h[n] = 0.f;
  float dts = 0.f;

  const ushort_t* drow = delta + r0 * D_INNER + d;
  const ushort_t* urow = xcb + r0 * D_INNER + d;

  float pdt[4], pu[4];
#pragma unroll
  for (int g = 0; g < 4; ++g) {
    pdt[g] = bf2f(drow[(size_t)g * D_INNER]);
    pu[g]  = bf2f(urow[(size_t)g * D_INNER]);
  }
  __syncthreads();

  for (int l0 = 0; l0 < CS; l0 += 4) {
    float cdt[4], cu[4];
#pragma unroll
    for (int g = 0; g < 4; ++g) { cdt[g] = pdt[g]; cu[g] = pu[g]; }
    if (l0 + 4 < CS) {
#pragma unroll
      for (int g = 0; g < 4; ++g) {
        pdt[g] = bf2f(drow[(size_t)(l0 + 4 + g) * D_INNER]);
        pu[g]  = bf2f(urow[(size_t)(l0 + 4 + g) * D_INNER]);
      }
    }
#pragma unroll
    for (int g = 0; g < 4; ++g) {
      int l = l0 + g;
      f32x4 B0 = *reinterpret_cast<const f32x4*>(&Bls[l][0]);
      f32x4 B1 = *reinterpret_cast<const f32x4*>(&Bls[l][4]);
      f32x4 B2 = *reinterpret_cast<const f32x4*>(&Bls[l][8]);
      f32x4 B3 = *reinterpret_cast<const f32x4*>(&Bls[l][12]);
      float du = cdt[g] * cu[g];
      dts += cdt[g];
      float Bsr[D_STATE] = {B0[0],B0[1],B0[2],B0[3], B1[0],B1[1],B1[2],B1[3],
                            B2[0],B2[1],B2[2],B2[3], B3[0],B3[1],B3[2],B3[3]};
#pragma unroll
      for (int n = 0; n < D_STATE; ++n) {
        float dA = __builtin_amdgcn_exp2f(cdt[g] * Av2[n]);
        h[n] = dA * h[n] + du * Bsr[n];
      }
    }
  }
#pragma unroll
  for (int n = 0; n < D_STATE; ++n)
    harr[((size_t)bc * D_STATE + n) * D_INNER + d] = h[n];
  dtsum[(size_t)bc * D_INNER + d] = dts;
}

// pass2: sequential combine over NC chunks; IN-PLACE: harr[c] := h0 for chunk c
__global__ __launch_bounds__(256) void scan_pass2(
    float* __restrict__ harr,
    const float* __restrict__ dtsum,
    const float* __restrict__ A_log) {
  int gid = blockIdx.x * 256 + threadIdx.x;
  int d = gid & (D_INNER - 1);
  int bn = gid >> 11;
  int n = bn & (D_STATE - 1);
  int b = bn >> 4;
  float Av2 = -__expf(A_log[(size_t)d * D_STATE + n]) * LOG2E;
  float h = 0.f;
  for (int c = 0; c < NC; ++c) {
    size_t bc = (size_t)b * NC + c;
    size_t idx = (bc * D_STATE + n) * D_INNER + d;
    float he = harr[idx];
    harr[idx] = h;
    float P = __builtin_amdgcn_exp2f(Av2 * dtsum[bc * D_INNER + d]);
    h = P * h + he;
  }
}

// pass3: rescan with true h0, y = h·C + u*D, gate silu(z) -> bf16
__global__ __launch_bounds__(256) void scan_pass3(
    const ushort_t* __restrict__ delta,   // bf16
    const ushort_t* __restrict__ xcb,
    ushort_t* __restrict__ ybf,
    const float* __restrict__ xdbl,
    const ushort_t* __restrict__ xzb,
    const float* __restrict__ A_log,
    const float* __restrict__ Dp,
    const float* __restrict__ harr) {
  __shared__ __align__(16) float BCls[CS][32];   // B at [0..16), C at [16..32)
  int gid = blockIdx.x * 256 + threadIdx.x;
  int d = gid & (D_INNER - 1);
  int bc = gid >> 11;
  int c = bc & (NC - 1);
  int b = bc >> NC_LOG;
  const size_t r0 = (size_t)b * SEQ + (size_t)c * CS;

  {
    int sl = threadIdx.x >> 3, sf = (threadIdx.x & 7) * 4;
    *reinterpret_cast<f32x4*>(&BCls[sl][sf]) =
        *reinterpret_cast<const f32x4*>(xdbl + (r0 + sl) * 96 + 64 + sf);
  }

  float Av2[D_STATE];
#pragma unroll
  for (int n = 0; n < D_STATE; ++n)
    Av2[n] = -__expf(A_log[(size_t)d * D_STATE + n]) * LOG2E;
  const float Dd = Dp[d];
  float h[D_STATE];
#pragma unroll
  for (int n = 0; n < D_STATE; ++n)
    h[n] = harr[((size_t)bc * D_STATE + n) * D_INNER + d];

  const ushort_t* drow = delta + r0 * D_INNER + d;
  const ushort_t* urow = xcb + r0 * D_INNER + d;
  const ushort_t* zrow = xzb + r0 * (2 * D_INNER) + D_INNER + d;
  ushort_t* yrow = ybf + r0 * D_INNER + d;

  float pdt[4], pu[4], pz[4];
#pragma unroll
  for (int g = 0; g < 4; ++g) {
    pdt[g] = bf2f(drow[(size_t)g * D_INNER]);
    pu[g]  = bf2f(urow[(size_t)g * D_INNER]);
    pz[g]  = bf2f(zrow[(size_t)g * (2 * D_INNER)]);
  }
  __syncthreads();

  for (int l0 = 0; l0 < CS; l0 += 4) {
    float cdt[4], cu[4], cz[4];
#pragma unroll
    for (int g = 0; g < 4; ++g) { cdt[g] = pdt[g]; cu[g] = pu[g]; cz[g] = pz[g]; }
    if (l0 + 4 < CS) {
#pragma unroll
      for (int g = 0; g < 4; ++g) {
        pdt[g] = bf2f(drow[(size_t)(l0 + 4 + g) * D_INNER]);
        pu[g]  = bf2f(urow[(size_t)(l0 + 4 + g) * D_INNER]);
        pz[g]  = bf2f(zrow[(size_t)(l0 + 4 + g) * (2 * D_INNER)]);
      }
    }
#pragma unroll
    for (int g = 0; g < 4; ++g) {
      int l = l0 + g;
      f32x4 B0 = *reinterpret_cast<const f32x4*>(&BCls[l][0]);
      f32x4 B1 = *reinterpret_cast<const f32x4*>(&BCls[l][4]);
      f32x4 B2 = *reinterpret_cast<const f32x4*>(&BCls[l][8]);
      f32x4 B3 = *reinterpret_cast<const f32x4*>(&BCls[l][12]);
      f32x4 C0 = *reinterpret_cast<const f32x4*>(&BCls[l][16]);
      f32x4 C1 = *reinterpret_cast<const f32x4*>(&BCls[l][20]);
      f32x4 C2 = *reinterpret_cast<const f32x4*>(&BCls[l][24]);
      f32x4 C3 = *reinterpret_cast<const f32x4*>(&BCls[l][28]);
      float du = cdt[g] * cu[g];
      float Bsr[D_STATE] = {B0[0],B0[1],B0[2],B0[3], B1[0],B1[1],B1[2],B1[3],
                            B2[0],B2[1],B2[2],B2[3], B3[0],B3[1],B3[2],B3[3]};
      float Csr[D_STATE] = {C0[0],C0[1],C0[2],C0[3], C1[0],C1[1],C1[2],C1[3],
                            C2[0],C2[1],C2[2],C2[3], C3[0],C3[1],C3[2],C3[3]};
      float y = 0.f;
#pragma unroll
      for (int n = 0; n < D_STATE; ++n) {
        float dA = __builtin_amdgcn_exp2f(cdt[g] * Av2[n]);
        h[n] = dA * h[n] + du * Bsr[n];
        y = fmaf(h[n], Csr[n], y);
      }
      y = fmaf(cu[g], Dd, y);
      yrow[(size_t)l * D_INNER] = f2bf(y * (cz[g] * sigmoidf_(cz[g])));
    }
  }
}

extern "C" void kernel_launch(void* const* d_in, const int* in_sizes, int n_in,
                              void* d_out, int out_size, void* d_ws, size_t ws_size,
                              hipStream_t stream) {
  const float* x         = (const float*)d_in[0];
  const float* in_proj_w = (const float*)d_in[1];
  const float* conv_w    = (const float*)d_in[2];
  const float* conv_b    = (const float*)d_in[3];
  const float* x_proj_w  = (const float*)d_in[4];
  const float* dt_proj_w = (const float*)d_in[5];
  const float* dt_proj_b = (const float*)d_in[6];
  const float* A_log     = (const float*)d_in[7];
  const float* Dp        = (const float*)d_in[8];
  const float* out_proj_w= (const float*)d_in[9];
  const float* rms_w     = (const float*)d_in[10];
  const float* ln_w      = (const float*)d_in[11];
  const float* ln_b      = (const float*)d_in[12];
  const float* ff_w1     = (const float*)d_in[13];
  const float* ff_b1     = (const float*)d_in[14];
  const float* ff_w2     = (const float*)d_in[15];
  const float* ff_b2     = (const float*)d_in[16];
  float* out = (float*)d_out;

  float* ws = (float*)d_ws;
  // ---- layout (float-word offsets); total end = 65,536,000 w = 250.0 MiB ----
  float* res     = ws;                              // [0, 4194304)
  float* dtsum   = ws + 4194304;                    // B*NC*D_INNER = 262,144 w
  float* xdbl    = ws + 8388608;                    // [8388608, 8781824)
  ushort_t* hbuf_bf = (ushort_t*)(ws + 8912896);    // 4M ushorts [8912896, 11010048)
  float*    pbuf    = ws + 11010048;                // x_proj partials 3.1M w
  ushort_t* y_bf    = (ushort_t*)(ws + 15204352);   // 8M ushorts [15204352, 19398656)
  ushort_t* glu_bf  = (ushort_t*)(ws + 11010048);   // overlays pbuf+y_bf (FFN phase)
  float* big   = ws + 19398656;                     // [19398656, 52953088)
  ushort_t* xz_bf = (ushort_t*)big;                 // 16.7M ushorts = 8,388,608 w (layer phase)
  ushort_t* xcb   = (ushort_t*)(big + 8388608);     // 8.4M ushorts = 4,194,304 w
  ushort_t* delta_bf = (ushort_t*)(big + 16777216); // 8.4M ushorts = 4,194,304 w (bf16 delta)
  float* harr  = big + 25165824;                    // B*NC*16*D_INNER = 4,194,304 w
  float* op_out= big;                               // 4M w (overlays xz_bf after scan)
  ushort_t* nrm_bf = (ushort_t*)(big + 16777216 + 4194304); // dead before dt_proj writes delta_bf
  ushort_t* in_w_bf  = (ushort_t*)(ws + 52953088);  // 8M ushorts [52953088, 57147392)
  ushort_t* out_w_bf = (ushort_t*)(ws + 57147392);  // 4M ushorts [57147392, 59244544)
  ushort_t* ff1_bf   = (ushort_t*)(ws + 59244544);  // 8M ushorts [59244544, 63438848)
  ushort_t* ff2_bf   = (ushort_t*)(ws + 63438848);  // 4M ushorts [63438848, 65536000)

  dim3 tb(16, 16);

  // all 4 weight conversions in one launch
  f2b_all<<<24576, 256, 0, stream>>>(in_proj_w, in_w_bf, out_proj_w, out_w_bf,
                                     ff_w1, ff1_bf, ff_w2, ff2_bf);

  // layer 0 input norm
  res_rms_kernel<<<ROWS, 256, 0, stream>>>(x, res, nrm_bf, rms_w);

  for (int i = 0; i < DEPTH; ++i) {
    const float* cw    = conv_w + (size_t)i * D_INNER * D_CONV;
    const float* cb    = conv_b + (size_t)i * D_INNER;
    const float* xp_w  = x_proj_w + (size_t)i * 96 * D_INNER;
    const float* dtp_w = dt_proj_w + (size_t)i * D_INNER * DT_RANK;
    const float* dtp_b = dt_proj_b + (size_t)i * D_INNER;
    const float* Alg   = A_log + (size_t)i * D_INNER * D_STATE;
    const float* Di    = Dp + (size_t)i * D_INNER;

    // in_proj: xz_bf[4096,4096] = nrm * in_w^T  (bf16 MFMA, dbuf+counted-vmcnt)
    gemm_bf16_nt<<<dim3(32, 32), 256, 0, stream>>>(
        nrm_bf, in_w_bf + (size_t)i * 4194304, nullptr, xz_bf, 2 * D_INNER, DIM,
        nullptr, 16);
    conv_silu_kernel<<<(ROWS * D_INNER / 4) / 256, 256, 0, stream>>>(xz_bf, xcb, cw, cb);
    // x_proj: split-K two-stage
    xproj_partial<<<dim3(XP_KS, 64), 256, 0, stream>>>(xcb, xp_w, pbuf);
    xproj_reduce<<<(ROWS * 96) / 256, 256, 0, stream>>>(pbuf, xdbl);
    // dt_proj + softplus -> bf16 delta
    gemm_nt<<<dim3(32, 64), tb, 0, stream>>>(xdbl, 96, dtp_w, DT_RANK, delta_bf,
                                             D_INNER, D_INNER, DT_RANK, dtp_b, 1);
    scan_pass1<<<(BATCH * NC * D_INNER) / 256, 256, 0, stream>>>(delta_bf, xcb, xdbl,
                                                                 Alg, harr, dtsum);
    scan_pass2<<<(BATCH * D_STATE * D_INNER) / 256, 256, 0, stream>>>(harr, dtsum, Alg);
    scan_pass3<<<(BATCH * NC * D_INNER) / 256, 256, 0, stream>>>(delta_bf, xcb, y_bf,
                                                                 xdbl, xz_bf, Alg, Di,
                                                                 harr);
    // out_proj: op_out[4096,1024] = y * o_w^T  (64x128 dbuf+counted-vmcnt); xz dead now
    gemm_bf16_nt64<<<dim3(8, 64), 256, 0, stream>>>(
        y_bf, out_w_bf + (size_t)i * 2097152, op_out, DIM, D_INNER, nullptr, 8);
    if (i + 1 < DEPTH) {
      ln_res_rms_kernel<<<ROWS, 256, 0, stream>>>(
          op_out, res, ln_w + (size_t)i * DIM, ln_b + (size_t)i * DIM,
          rms_w + (size_t)(i + 1) * DIM, nrm_bf);
    } else {
      ln_final_kernel<<<ROWS, 256, 0, stream>>>(
          op_out, hbuf_bf, ln_w + (size_t)i * DIM, ln_b + (size_t)i * DIM);
    }
  }

  // FFN1 + GEGLU fused (single-buffer 128x64-out; best per R15/R19 A/Bs)
  gemm_ffn1_glu<<<dim3(64, 32), 256, 0, stream>>>(hbuf_bf, ff1_bf, glu_bf, DIM,
                                                  ff_b1, 16);
  // FFN2: out = glu * ff_w2^T + b2  (64x128 dbuf+counted-vmcnt)
  gemm_bf16_nt64<<<dim3(8, 64), 256, 0, stream>>>(glu_bf, ff2_bf, out, DIM, FF,
                                                  ff_b2, 8);
}